// Round 3
// baseline (165.667 us; speedup 1.0000x reference)
//
#include <hip/hip_runtime.h>
#include <math.h>

// N=4096 nodes, D=256, S=32, K=4 heads, ETA=0.5.
// adj_mask is binary {0,1} (~2% density + self-loops): masked softmax ==
// exact sparse softmax over each row's neighbor set (exp(-1e9-max)==0 in fp32).
constexpr int NN = 4096;
constexpr int DD = 256;
constexpr int SS = 32;
constexpr int KK = 4;
constexpr int MAXN = 192;    // row degree: mean 83, sd 9 -> 192 = +12 sd
constexpr int SEGMAX = 96;   // per-quarter-row degree: mean ~21, sd 4.5
constexpr float ETA = 0.5f;

#define MEMFENCE() __asm__ volatile("" ::: "memory")

// __builtin_nontemporal_* needs scalar or NATIVE clang vector pointers, not
// HIP_vector_type. Use ext_vector_type(4) float (same 16B layout as float4).
typedef float nfloat4 __attribute__((ext_vector_type(4)));

__device__ __forceinline__ float4 ntload4(const float4* p) {
  nfloat4 v = __builtin_nontemporal_load((const nfloat4*)p);
  float4 r; r.x = v.x; r.y = v.y; r.z = v.z; r.w = v.w;
  return r;
}

// ---------------------------------------------------------------------------
// Kernel 1 (prep):
//   blocks [0,1024):  Z[k] = H @ U[k]; block b -> head k=b&3, nodes (b>>2)*16..+16
//   blocks [1024,1034): orth-loss partial for one (k<=l) pair -> lossp[pair];
//                       pair 0 also writes elp = exp(log_precision).
//   (H loads NOT nontemporal here: each 16-node tile is read by 4 head-blocks,
//    we want the L2 reuse.)
// ---------------------------------------------------------------------------
__global__ __launch_bounds__(256) void prep_kernel(
    const float* __restrict__ H, const float* __restrict__ U,
    const float* __restrict__ lp, float* __restrict__ Z,
    float* __restrict__ elp, float* __restrict__ lossp) {
  __shared__ float Hl[16][DD];   // 16 KB (Z path only)
  __shared__ float red[4];
  const int tid = threadIdx.x;

  if (blockIdx.x < 1024) {
    const int k = blockIdx.x & 3;
    const int n0 = (blockIdx.x >> 2) * 16;

    const float4* H4 = (const float4*)(H + (size_t)n0 * DD);
    float4* Hl4 = (float4*)&Hl[0][0];
    for (int i = tid; i < 16 * DD / 4; i += 256) Hl4[i] = H4[i];
    __syncthreads();

    const int s = tid & 31;
    const int n_l = (tid >> 5) & 7;   // 0..7; thread owns nodes n_l and n_l+8
    const float* Uk = U + (size_t)k * DD * SS;
    float acc0 = 0.f, acc1 = 0.f;
#pragma unroll 4
    for (int dq = 0; dq < DD / 4; dq++) {
      const float4 h0 = Hl4[n_l * (DD / 4) + dq];        // LDS broadcast b128
      const float4 h1 = Hl4[(n_l + 8) * (DD / 4) + dq];
      const float u0 = Uk[(4 * dq + 0) * SS + s];        // coalesced 128B
      const float u1 = Uk[(4 * dq + 1) * SS + s];
      const float u2 = Uk[(4 * dq + 2) * SS + s];
      const float u3 = Uk[(4 * dq + 3) * SS + s];
      acc0 += h0.x * u0 + h0.y * u1 + h0.z * u2 + h0.w * u3;
      acc1 += h1.x * u0 + h1.y * u1 + h1.z * u2 + h1.w * u3;
    }
    Z[((size_t)k * NN + n0 + n_l) * SS + s] = acc0;
    Z[((size_t)k * NN + n0 + n_l + 8) * SS + s] = acc1;
  } else {
    // ---- orth path: one (k<=l) pair per block ----
    const int pair = blockIdx.x - 1024;
    if (pair == 0 && tid < KK * SS) elp[tid] = expf(lp[tid]);
    const int pk[10] = {0, 0, 0, 0, 1, 1, 1, 2, 2, 3};
    const int pl[10] = {0, 1, 2, 3, 1, 2, 3, 2, 3, 3};
    const int k = pk[pair], l = pl[pair];
    const int b = tid & 31;
    const int a0 = tid >> 5;          // cell a = a0 + 8*j
    float acc[4] = {0.f, 0.f, 0.f, 0.f};
    for (int d = 0; d < DD; d++) {
      const float ub = U[((size_t)l * DD + d) * SS + b];
#pragma unroll
      for (int j = 0; j < 4; j++)
        acc[j] += U[((size_t)k * DD + d) * SS + a0 + 8 * j] * ub;
    }
    float tot = 0.f;
#pragma unroll
    for (int j = 0; j < 4; j++) {
      const float cv = acc[j] - ((k == l && (a0 + 8 * j) == b) ? 1.0f : 0.0f);
      tot += cv * cv;
    }
#pragma unroll
    for (int off = 32; off >= 1; off >>= 1) tot += __shfl_xor(tot, off);
    if ((tid & 63) == 0) red[tid >> 6] = tot;
    __syncthreads();
    if (tid == 0) lossp[pair] = red[0] + red[1] + red[2] + red[3];
  }
}

// ---------------------------------------------------------------------------
// Kernel 2: one ROW per block, one HEAD per wave (4 waves).
//   Scan: ballot-compact the mask row (nontemporal loads: mask is 64 MB,
//     zero reuse -- keep it out of L2 so the 2 MB Z working set stays hot).
//   Head (wave k): single-pass online softmax, BRANCHLESS rescale,
//     2-deep software pipeline: chunk i+1's nbr[] reads + Z gathers are
//     issued before chunk i's shuffle/exp chain, hiding one L2 latency
//     per iteration.
// ---------------------------------------------------------------------------
__global__ __launch_bounds__(256) void attn_row(
    const float* __restrict__ mask, const float* __restrict__ Z,
    const float* __restrict__ elp, const float* __restrict__ lossp,
    float* __restrict__ AO, float* __restrict__ loss) {
  const int tid = threadIdx.x;
  const int wv = tid >> 6;
  const int lane = tid & 63;
  const int row = blockIdx.x;

  __shared__ int segn[4][SEGMAX];
  __shared__ int segc[4];
  __shared__ int nbr[MAXN];

  if (blockIdx.x == 0 && tid == 0) {
    float t = 0.f;
#pragma unroll
    for (int i = 0; i < 10; i++) t += lossp[i];
    loss[0] = t;
  }

  // --- scan: wave wv covers float4 indices [wv*256, wv*256+256) of the row ---
  const float4* m4 = (const float4*)(mask + (size_t)row * NN);
  const unsigned long long lt = (1ULL << lane) - 1ULL;
  int cnt = 0;
#pragma unroll
  for (int it = 0; it < 4; it++) {
    const int i = wv * 256 + it * 64 + lane;   // coalesced within wave
    const float4 v = ntload4(&m4[i]);
    unsigned long long b;
    b = __ballot(v.x > 0.5f);
    if (v.x > 0.5f) { const int p = cnt + (int)__popcll(b & lt); if (p < SEGMAX) segn[wv][p] = 4 * i; }
    cnt += (int)__popcll(b);
    b = __ballot(v.y > 0.5f);
    if (v.y > 0.5f) { const int p = cnt + (int)__popcll(b & lt); if (p < SEGMAX) segn[wv][p] = 4 * i + 1; }
    cnt += (int)__popcll(b);
    b = __ballot(v.z > 0.5f);
    if (v.z > 0.5f) { const int p = cnt + (int)__popcll(b & lt); if (p < SEGMAX) segn[wv][p] = 4 * i + 2; }
    cnt += (int)__popcll(b);
    b = __ballot(v.w > 0.5f);
    if (v.w > 0.5f) { const int p = cnt + (int)__popcll(b & lt); if (p < SEGMAX) segn[wv][p] = 4 * i + 3; }
    cnt += (int)__popcll(b);
  }
  if (lane == 0) segc[wv] = min(cnt, SEGMAX);
  MEMFENCE();
  __syncthreads();

  // --- merge segments into packed nbr[] ---
  const int c0 = segc[0], c1 = segc[1], c2 = segc[2], c3 = segc[3];
  const int offs[4] = {0, c0, c0 + c1, c0 + c1 + c2};
  const int c = min(c0 + c1 + c2 + c3, MAXN);
  const int myc = segc[wv];
  const int myoff = offs[wv];
  for (int i = lane; i < myc; i += 64) {
    const int p = myoff + i;
    if (p < MAXN) nbr[p] = segn[wv][i];
  }
  MEMFENCE();
  __syncthreads();

  // --- head k = wv: single-pass online softmax, pipelined gathers ---
  const int k = wv;
  const int p_sub = lane >> 3;   // neighbor slot within chunk (bits 3..5)
  const int sq = lane & 7;       // float4 slice of the 32-dim row (bits 0..2)
  const float inv_sqrt_s = 0.17677669529663687f;  // 1/sqrt(32)
  const float* Zk = Z + (size_t)k * NN * SS;

  // query quad: q4 = Z[k][row][4sq..] * exp(lp[k][...])  (broadcast loads)
  float4 q4;
  {
    const float4 a = ((const float4*)(Z + ((size_t)k * NN + row) * SS))[sq];
    const float4 e = ((const float4*)(elp + k * SS))[sq];
    q4.x = a.x * e.x; q4.y = a.y * e.y; q4.z = a.z * e.z; q4.w = a.w * e.w;
  }

  float m = -3.0e38f;
  float wsum = 0.f;
  float4 o4 = {0.f, 0.f, 0.f, 0.f};

  // prologue: load chunk 0
  bool aA = p_sub < c, aB = (p_sub + 8) < c;
  float4 zA = {0.f, 0.f, 0.f, 0.f}, zB = {0.f, 0.f, 0.f, 0.f};
  if (aA) zA = ((const float4*)(Zk + (size_t)nbr[p_sub] * SS))[sq];
  if (aB) zB = ((const float4*)(Zk + (size_t)nbr[p_sub + 8] * SS))[sq];

  for (int p0 = 0; p0 < c; p0 += 16) {
    // ---- issue next chunk's gathers first (overlap with this chunk's math) --
    const int pa_n = p0 + 16 + p_sub;
    const int pb_n = pa_n + 8;
    const bool aA_n = pa_n < c, aB_n = pb_n < c;
    float4 zA_n = {0.f, 0.f, 0.f, 0.f}, zB_n = {0.f, 0.f, 0.f, 0.f};
    if (aA_n) zA_n = ((const float4*)(Zk + (size_t)nbr[pa_n] * SS))[sq];
    if (aB_n) zB_n = ((const float4*)(Zk + (size_t)nbr[pb_n] * SS))[sq];

    // ---- process current chunk ----
    float dA = q4.x * zA.x + q4.y * zA.y + q4.z * zA.z + q4.w * zA.w;
    float dB = q4.x * zB.x + q4.y * zB.y + q4.z * zB.z + q4.w * zB.w;
    dA += __shfl_xor(dA, 1); dB += __shfl_xor(dB, 1);
    dA += __shfl_xor(dA, 2); dB += __shfl_xor(dB, 2);
    dA += __shfl_xor(dA, 4); dB += __shfl_xor(dB, 4);  // full dot in all sq lanes
    dA = aA ? dA * inv_sqrt_s : -3.0e38f;
    dB = aB ? dB * inv_sqrt_s : -3.0e38f;
    // chunk max across p_sub lanes -> uniform across the whole wave
    float cm = fmaxf(dA, dB);
    cm = fmaxf(cm, __shfl_xor(cm, 8));
    cm = fmaxf(cm, __shfl_xor(cm, 16));
    cm = fmaxf(cm, __shfl_xor(cm, 32));
    // branchless online rescale: m=-3e38 first iter -> sc = exp(-inf) = 0
    const float mn = fmaxf(m, cm);
    const float sc = __expf(m - mn);
    m = mn;
    const float wA = __expf(dA - m);     // invalid slot: exp(-3e38-m) == 0
    const float wB = __expf(dB - m);
    o4.x = o4.x * sc + wA * zA.x + wB * zB.x;
    o4.y = o4.y * sc + wA * zA.y + wB * zB.y;
    o4.z = o4.z * sc + wA * zA.z + wB * zB.z;
    o4.w = o4.w * sc + wA * zA.w + wB * zB.w;
    wsum = wsum * sc + wA + wB;   // dup across sq lanes; reduced over p_sub below

    // ---- rotate pipeline ----
    zA = zA_n; zB = zB_n; aA = aA_n; aB = aB_n;
  }
#pragma unroll
  for (int off = 8; off <= 32; off <<= 1) {
    o4.x += __shfl_xor(o4.x, off);
    o4.y += __shfl_xor(o4.y, off);
    o4.z += __shfl_xor(o4.z, off);
    o4.w += __shfl_xor(o4.w, off);
    wsum += __shfl_xor(wsum, off);
  }
  const float invl = 1.0f / wsum;   // c >= 1 (self-loop) -> wsum > 0
  if (p_sub == 0) {
    float4 o;
    o.x = o4.x * invl; o.y = o4.y * invl; o.z = o4.z * invl; o.w = o4.w * invl;
    ((float4*)AO)[(size_t)row * (KK * SS / 4) + k * 8 + sq] = o;  // 128B/wave
  }
}

// ---------------------------------------------------------------------------
// Kernel 3 (epilogue): Hout = softthresh(H + ETA * AO @ Ufl), Ufl[(k,s)][d]=U[k][d][s].
// 4 rows per block, 1024 blocks; d = tid; AO tile staged in LDS.
// H load + Hout store are stream-once -> nontemporal (scalar float ptrs: legal).
// ---------------------------------------------------------------------------
__global__ __launch_bounds__(256) void epilogue_kernel(
    const float* __restrict__ H, const float* __restrict__ U,
    const float* __restrict__ thr, const float* __restrict__ AO,
    float* __restrict__ Hout) {
  __shared__ float AOl[4][KK * SS];   // 2 KB
  const int tid = threadIdx.x;
  const int r0 = blockIdx.x * 4;

  const float4* AO4 = (const float4*)(AO + (size_t)r0 * KK * SS);
  float4* AOl4 = (float4*)&AOl[0][0];
  if (tid < 128) AOl4[tid] = AO4[tid];
  __syncthreads();

  const int d = tid;
  float acc[4] = {0.f, 0.f, 0.f, 0.f};
  const float4* U4 = (const float4*)U;
#pragma unroll
  for (int k = 0; k < KK; k++) {
    const int ubase = (k * DD + d) * (SS / 4);
#pragma unroll
    for (int sq = 0; sq < SS / 4; sq++) {
      const float4 u = U4[ubase + sq];   // thread's 128B row of U[k][d][:]
#pragma unroll
      for (int r = 0; r < 4; r++) {
        const float4 a = AOl4[r * (KK * SS / 4) + k * (SS / 4) + sq];  // LDS b128
        acc[r] += u.x * a.x + u.y * a.y + u.z * a.z + u.w * a.w;
      }
    }
  }
  const float tv = thr[d];
#pragma unroll
  for (int r = 0; r < 4; r++) {
    const float h = __builtin_nontemporal_load(&H[(size_t)(r0 + r) * DD + d]) + ETA * acc[r];
    const float ab = fabsf(h) - tv;
    const float o = (ab > 0.0f) ? copysignf(ab, h) : 0.0f;
    __builtin_nontemporal_store(o, &Hout[(size_t)(r0 + r) * DD + d]);
  }
}

// ---------------------------------------------------------------------------
extern "C" void kernel_launch(void* const* d_in, const int* in_sizes, int n_in,
                              void* d_out, int out_size, void* d_ws, size_t ws_size,
                              hipStream_t stream) {
  const float* H    = (const float*)d_in[0];
  const float* mask = (const float*)d_in[1];
  const float* U    = (const float*)d_in[2];
  const float* lp   = (const float*)d_in[3];
  const float* thr  = (const float*)d_in[4];

  float* Hout = (float*)d_out;
  float* loss = Hout + (size_t)NN * DD;      // outputs: [N*D] + [1]

  float* Z     = (float*)d_ws;               // [K][N][S]   2 MB (16B aligned)
  float* AO    = Z + (size_t)KK * NN * SS;   // [N][K*S]    2 MB (16B aligned)
  float* elp   = AO + (size_t)NN * KK * SS;  // [K*S]       (16B aligned)
  float* lossp = elp + KK * SS;              // [10]

  prep_kernel<<<1034, 256, 0, stream>>>(H, U, lp, Z, elp, lossp);
  attn_row<<<NN, 256, 0, stream>>>(mask, Z, elp, lossp, AO, loss);
  epilogue_kernel<<<NN / 4, 256, 0, stream>>>(H, U, thr, AO, Hout);
}

// Round 5
// 164.356 us; speedup vs baseline: 1.0080x; 1.0080x over previous
//
#include <hip/hip_runtime.h>
#include <math.h>

// N=4096 nodes, D=256, S=32, K=4 heads, ETA=0.5.
// adj_mask is binary {0,1} (~2% density + self-loops): masked softmax ==
// exact sparse softmax over each row's neighbor set (exp(-1e9-max)==0 in fp32).
constexpr int NN = 4096;
constexpr int DD = 256;
constexpr int SS = 32;
constexpr int KK = 4;
constexpr int MAXN = 192;    // row degree: mean 83, sd 9 -> 192 = +12 sd
constexpr int SEGMAX = 96;   // per-quarter-row degree: mean ~21, sd 4.5
constexpr float ETA = 0.5f;

#define MEMFENCE() __asm__ volatile("" ::: "memory")

// __builtin_nontemporal_* needs scalar or NATIVE clang vector pointers.
typedef float nfloat4 __attribute__((ext_vector_type(4)));
__device__ __forceinline__ float4 ntload4(const float4* p) {
  nfloat4 v = __builtin_nontemporal_load((const nfloat4*)p);
  float4 r; r.x = v.x; r.y = v.y; r.z = v.z; r.w = v.w;
  return r;
}

// ---------------------------------------------------------------------------
// Kernel 1 (prep) -- identical to the round-3 PASSING version:
//   blocks [0,1024):  Z[k] = H @ U[k]; block b -> head k=b&3, nodes (b>>2)*16..+16
//   blocks [1024,1034): orth-loss partial for one (k<=l) pair -> lossp[pair];
//                       pair 0 also writes elp = exp(log_precision).
// ---------------------------------------------------------------------------
__global__ __launch_bounds__(256) void prep_kernel(
    const float* __restrict__ H, const float* __restrict__ U,
    const float* __restrict__ lp, float* __restrict__ Z,
    float* __restrict__ elp, float* __restrict__ lossp) {
  __shared__ float Hl[16][DD];   // 16 KB (Z path only)
  __shared__ float red[4];
  const int tid = threadIdx.x;

  if (blockIdx.x < 1024) {
    const int k = blockIdx.x & 3;
    const int n0 = (blockIdx.x >> 2) * 16;

    const float4* H4 = (const float4*)(H + (size_t)n0 * DD);
    float4* Hl4 = (float4*)&Hl[0][0];
    for (int i = tid; i < 16 * DD / 4; i += 256) Hl4[i] = H4[i];
    __syncthreads();

    const int s = tid & 31;
    const int n_l = (tid >> 5) & 7;   // 0..7; thread owns nodes n_l and n_l+8
    const float* Uk = U + (size_t)k * DD * SS;
    float acc0 = 0.f, acc1 = 0.f;
#pragma unroll 4
    for (int dq = 0; dq < DD / 4; dq++) {
      const float4 h0 = Hl4[n_l * (DD / 4) + dq];        // LDS broadcast b128
      const float4 h1 = Hl4[(n_l + 8) * (DD / 4) + dq];
      const float u0 = Uk[(4 * dq + 0) * SS + s];        // coalesced 128B
      const float u1 = Uk[(4 * dq + 1) * SS + s];
      const float u2 = Uk[(4 * dq + 2) * SS + s];
      const float u3 = Uk[(4 * dq + 3) * SS + s];
      acc0 += h0.x * u0 + h0.y * u1 + h0.z * u2 + h0.w * u3;
      acc1 += h1.x * u0 + h1.y * u1 + h1.z * u2 + h1.w * u3;
    }
    Z[((size_t)k * NN + n0 + n_l) * SS + s] = acc0;
    Z[((size_t)k * NN + n0 + n_l + 8) * SS + s] = acc1;
  } else {
    // ---- orth path: one (k<=l) pair per block ----
    const int pair = blockIdx.x - 1024;
    if (pair == 0 && tid < KK * SS) elp[tid] = expf(lp[tid]);
    const int pk[10] = {0, 0, 0, 0, 1, 1, 1, 2, 2, 3};
    const int pl[10] = {0, 1, 2, 3, 1, 2, 3, 2, 3, 3};
    const int k = pk[pair], l = pl[pair];
    const int b = tid & 31;
    const int a0 = tid >> 5;             // cells a = 4*a0 .. 4*a0+3 (contiguous)
    float4 acc = {0.f, 0.f, 0.f, 0.f};
    const float4* Uk4 = (const float4*)(U + (size_t)k * DD * SS);
    const float* Ul = U + (size_t)l * DD * SS;
    for (int d = 0; d < DD; d++) {
      const float ub = Ul[(size_t)d * SS + b];             // coalesced 128B
      const float4 ua = Uk4[d * (SS / 4) + a0];            // 2 VMEM/d total
      acc.x += ua.x * ub; acc.y += ua.y * ub;
      acc.z += ua.z * ub; acc.w += ua.w * ub;
    }
    const int abase = 4 * a0;
    float cvx = acc.x - ((k == l && abase + 0 == b) ? 1.0f : 0.0f);
    float cvy = acc.y - ((k == l && abase + 1 == b) ? 1.0f : 0.0f);
    float cvz = acc.z - ((k == l && abase + 2 == b) ? 1.0f : 0.0f);
    float cvw = acc.w - ((k == l && abase + 3 == b) ? 1.0f : 0.0f);
    float tot = cvx * cvx + cvy * cvy + cvz * cvz + cvw * cvw;
#pragma unroll
    for (int off = 32; off >= 1; off >>= 1) tot += __shfl_xor(tot, off);
    if ((tid & 63) == 0) red[tid >> 6] = tot;
    __syncthreads();
    if (tid == 0) lossp[pair] = red[0] + red[1] + red[2] + red[3];
  }
}

// ---------------------------------------------------------------------------
// Kernel 2 (attn + fused epilogue): 4 ROWS per block, 1024 blocks.
//   Per row: scan mask row (nt loads) -> ballot-compact nbr[] -> per-wave
//   head, single-pass online softmax with 2-deep pipelined gathers; AO row
//   written to LDS (AOl[4][K*S]) instead of global.
//   Then per-block epilogue: Hout = softthresh(H + ETA * AOl @ Ufl) for the
//   4 rows, straight from LDS. AO global round-trip + 3rd dispatch removed.
// ---------------------------------------------------------------------------
__global__ __launch_bounds__(256) void attn_epi(
    const float* __restrict__ mask, const float* __restrict__ Z,
    const float* __restrict__ elp, const float* __restrict__ lossp,
    const float* __restrict__ H, const float* __restrict__ U,
    const float* __restrict__ thr, float* __restrict__ Hout,
    float* __restrict__ loss) {
  const int tid = threadIdx.x;
  const int wv = tid >> 6;
  const int lane = tid & 63;
  const int bid = blockIdx.x;

  __shared__ int segn[4][SEGMAX];
  __shared__ int segc[4];
  __shared__ int nbr[MAXN];
  __shared__ float AOl[4][KK * SS];   // 2 KB: the 4 rows' attention outputs

  if (bid == 0 && tid == 0) {
    float t = 0.f;
#pragma unroll
    for (int i = 0; i < 10; i++) t += lossp[i];
    loss[0] = t;
  }

  const int p_sub = lane >> 3;   // neighbor slot within chunk (bits 3..5)
  const int sq = lane & 7;       // float4 slice of the 32-dim row (bits 0..2)
  const float inv_sqrt_s = 0.17677669529663687f;  // 1/sqrt(32)
  const unsigned long long lt = (1ULL << lane) - 1ULL;
  const int k = wv;
  const float* Zk = Z + (size_t)k * NN * SS;

  for (int r = 0; r < 4; r++) {
    const int row = bid * 4 + r;
    if (r) __syncthreads();   // protect segn/nbr reuse across rows

    // --- scan: wave wv covers float4 indices [wv*256, wv*256+256) ---
    const float4* m4 = (const float4*)(mask + (size_t)row * NN);
    int cnt = 0;
#pragma unroll
    for (int it = 0; it < 4; it++) {
      const int i = wv * 256 + it * 64 + lane;   // coalesced within wave
      const float4 v = ntload4(&m4[i]);          // nt: mask has zero reuse
      unsigned long long bb;
      bb = __ballot(v.x > 0.5f);
      if (v.x > 0.5f) { const int p = cnt + (int)__popcll(bb & lt); if (p < SEGMAX) segn[wv][p] = 4 * i; }
      cnt += (int)__popcll(bb);
      bb = __ballot(v.y > 0.5f);
      if (v.y > 0.5f) { const int p = cnt + (int)__popcll(bb & lt); if (p < SEGMAX) segn[wv][p] = 4 * i + 1; }
      cnt += (int)__popcll(bb);
      bb = __ballot(v.z > 0.5f);
      if (v.z > 0.5f) { const int p = cnt + (int)__popcll(bb & lt); if (p < SEGMAX) segn[wv][p] = 4 * i + 2; }
      cnt += (int)__popcll(bb);
      bb = __ballot(v.w > 0.5f);
      if (v.w > 0.5f) { const int p = cnt + (int)__popcll(bb & lt); if (p < SEGMAX) segn[wv][p] = 4 * i + 3; }
      cnt += (int)__popcll(bb);
    }
    if (lane == 0) segc[wv] = min(cnt, SEGMAX);
    MEMFENCE();
    __syncthreads();

    // --- merge segments into packed nbr[] ---
    const int c0 = segc[0], c1 = segc[1], c2 = segc[2], c3 = segc[3];
    const int offs[4] = {0, c0, c0 + c1, c0 + c1 + c2};
    const int c = min(c0 + c1 + c2 + c3, MAXN);
    const int myc = segc[wv];
    const int myoff = offs[wv];
    for (int i = lane; i < myc; i += 64) {
      const int p = myoff + i;
      if (p < MAXN) nbr[p] = segn[wv][i];
    }
    MEMFENCE();
    __syncthreads();

    // --- head k = wv: single-pass online softmax, pipelined gathers ---
    float4 q4;
    {
      const float4 a = ((const float4*)(Z + ((size_t)k * NN + row) * SS))[sq];
      const float4 e = ((const float4*)(elp + k * SS))[sq];
      q4.x = a.x * e.x; q4.y = a.y * e.y; q4.z = a.z * e.z; q4.w = a.w * e.w;
    }

    float m = -3.0e38f;
    float wsum = 0.f;
    float4 o4 = {0.f, 0.f, 0.f, 0.f};

    bool aA = p_sub < c, aB = (p_sub + 8) < c;
    float4 zA = {0.f, 0.f, 0.f, 0.f}, zB = {0.f, 0.f, 0.f, 0.f};
    if (aA) zA = ((const float4*)(Zk + (size_t)nbr[p_sub] * SS))[sq];
    if (aB) zB = ((const float4*)(Zk + (size_t)nbr[p_sub + 8] * SS))[sq];

    for (int p0 = 0; p0 < c; p0 += 16) {
      // issue next chunk's gathers first (overlap with this chunk's math)
      const int pa_n = p0 + 16 + p_sub;
      const int pb_n = pa_n + 8;
      const bool aA_n = pa_n < c, aB_n = pb_n < c;
      float4 zA_n = {0.f, 0.f, 0.f, 0.f}, zB_n = {0.f, 0.f, 0.f, 0.f};
      if (aA_n) zA_n = ((const float4*)(Zk + (size_t)nbr[pa_n] * SS))[sq];
      if (aB_n) zB_n = ((const float4*)(Zk + (size_t)nbr[pb_n] * SS))[sq];

      float dA = q4.x * zA.x + q4.y * zA.y + q4.z * zA.z + q4.w * zA.w;
      float dB = q4.x * zB.x + q4.y * zB.y + q4.z * zB.z + q4.w * zB.w;
      dA += __shfl_xor(dA, 1); dB += __shfl_xor(dB, 1);
      dA += __shfl_xor(dA, 2); dB += __shfl_xor(dB, 2);
      dA += __shfl_xor(dA, 4); dB += __shfl_xor(dB, 4);  // full dot, all sq lanes
      dA = aA ? dA * inv_sqrt_s : -3.0e38f;
      dB = aB ? dB * inv_sqrt_s : -3.0e38f;
      float cm = fmaxf(dA, dB);
      cm = fmaxf(cm, __shfl_xor(cm, 8));
      cm = fmaxf(cm, __shfl_xor(cm, 16));
      cm = fmaxf(cm, __shfl_xor(cm, 32));
      const float mn = fmaxf(m, cm);
      const float sc = __expf(m - mn);   // first iter: exp(-inf) == 0
      m = mn;
      const float wA = __expf(dA - m);   // invalid slot: exp(-3e38-m) == 0
      const float wB = __expf(dB - m);
      o4.x = o4.x * sc + wA * zA.x + wB * zB.x;
      o4.y = o4.y * sc + wA * zA.y + wB * zB.y;
      o4.z = o4.z * sc + wA * zA.z + wB * zB.z;
      o4.w = o4.w * sc + wA * zA.w + wB * zB.w;
      wsum = wsum * sc + wA + wB;

      zA = zA_n; zB = zB_n; aA = aA_n; aB = aB_n;
    }
#pragma unroll
    for (int off = 8; off <= 32; off <<= 1) {
      o4.x += __shfl_xor(o4.x, off);
      o4.y += __shfl_xor(o4.y, off);
      o4.z += __shfl_xor(o4.z, off);
      o4.w += __shfl_xor(o4.w, off);
      wsum += __shfl_xor(wsum, off);
    }
    const float invl = 1.0f / wsum;   // c >= 1 (self-loop) -> wsum > 0
    if (p_sub == 0) {
      float4 o;
      o.x = o4.x * invl; o.y = o4.y * invl;
      o.z = o4.z * invl; o.w = o4.w * invl;
      ((float4*)&AOl[r][0])[k * 8 + sq] = o;   // AO row stays in LDS
    }
  }
  MEMFENCE();
  __syncthreads();

  // --- fused epilogue: Hout = softthresh(H + ETA * AOl @ Ufl), rows bid*4.. ---
  {
    const int r0 = bid * 4;
    const int d = tid;
    float acc[4] = {0.f, 0.f, 0.f, 0.f};
    const float4* U4 = (const float4*)U;
    const float4* AOl4 = (const float4*)&AOl[0][0];
#pragma unroll
    for (int kk = 0; kk < KK; kk++) {
      const int ubase = (kk * DD + d) * (SS / 4);
#pragma unroll
      for (int sq2 = 0; sq2 < SS / 4; sq2++) {
        const float4 u = U4[ubase + sq2];   // thread's 128B row of U[kk][d][:]
#pragma unroll
        for (int r = 0; r < 4; r++) {
          const float4 a = AOl4[r * (KK * SS / 4) + kk * (SS / 4) + sq2];
          acc[r] += u.x * a.x + u.y * a.y + u.z * a.z + u.w * a.w;
        }
      }
    }
    const float tv = thr[d];
#pragma unroll
    for (int r = 0; r < 4; r++) {
      const float h =
          __builtin_nontemporal_load(&H[(size_t)(r0 + r) * DD + d]) + ETA * acc[r];
      const float ab = fabsf(h) - tv;
      const float o = (ab > 0.0f) ? copysignf(ab, h) : 0.0f;
      __builtin_nontemporal_store(o, &Hout[(size_t)(r0 + r) * DD + d]);
    }
  }
}

// ---------------------------------------------------------------------------
extern "C" void kernel_launch(void* const* d_in, const int* in_sizes, int n_in,
                              void* d_out, int out_size, void* d_ws, size_t ws_size,
                              hipStream_t stream) {
  const float* H    = (const float*)d_in[0];
  const float* mask = (const float*)d_in[1];
  const float* U    = (const float*)d_in[2];
  const float* lp   = (const float*)d_in[3];
  const float* thr  = (const float*)d_in[4];

  float* Hout = (float*)d_out;
  float* loss = Hout + (size_t)NN * DD;      // outputs: [N*D] + [1]

  float* Z     = (float*)d_ws;               // [K][N][S]   2 MB (16B aligned)
  float* elp   = Z + (size_t)KK * NN * SS;   // [K*S]
  float* lossp = elp + KK * SS;              // [10]

  prep_kernel<<<1034, 256, 0, stream>>>(H, U, lp, Z, elp, lossp);
  attn_epi<<<NN / 4, 256, 0, stream>>>(mask, Z, elp, lossp, H, U, thr, Hout, loss);
}